// Round 6
// baseline (477.803 us; speedup 1.0000x reference)
//
#include <hip/hip_runtime.h>

#define N_NODES 50000
#define N_EDGES 600000
#define N_RELS  19
#define D_IN    128
#define D_HID   64
#define D_OUT   2

typedef unsigned short u16;
typedef unsigned int   u32;
typedef __attribute__((ext_vector_type(8))) short sfrag;   // 8 bf16 (4 VGPRs)
typedef __attribute__((ext_vector_type(4))) float f32x4;   // 4 fp32 acc

__device__ __forceinline__ u16 f2bf(float f){
  union { float f; u32 i; } v; v.f = f;
  u32 r = v.i + 0x7fffu + ((v.i >> 16) & 1u);  // RNE
  return (u16)(r >> 16);
}
__device__ __forceinline__ float bf2f(u16 u){
  union { u32 i; float f; } v; v.i = ((u32)u) << 16; return v.f;
}

// feat fp32 -> featb bf16 (packed u32 pairs)
__global__ __launch_bounds__(256) void k_featb(const float* __restrict__ feat,
                                               u16* __restrict__ featb){
  int i = blockIdx.x * 256 + threadIdx.x;
  float2 f = ((const float2*)feat)[i];
  ((u32*)featb)[i] = (u32)f2bf(f.x) | ((u32)f2bf(f.y) << 16);
}

// Weights: W1Tb [19][64][128], W2Tb [19][16][64] (cols>=2 zero), loop1Tb [64][128] (all bf16, B^T)
__global__ void k_prep(const float* __restrict__ W1, const float* __restrict__ loop1,
                       const float* __restrict__ W2,
                       u16* __restrict__ W1Tb, u16* __restrict__ loop1Tb,
                       u16* __restrict__ W2Tb){
  int idx = blockIdx.x * 256 + threadIdx.x;
  const int T1 = N_RELS * D_HID * D_IN;        // 155648
  const int T2 = T1 + N_RELS * 16 * D_HID;     // +19456
  const int T3 = T2 + D_HID * D_IN;            // +8192
  if (idx < T1) {
    int r = idx / (D_HID * D_IN);
    int t = idx - r * (D_HID * D_IN);
    int j = t >> 7, d = t & 127;
    W1Tb[idx] = f2bf(W1[(r * D_IN + d) * D_HID + j]);
  } else if (idx < T2) {
    int k2 = idx - T1;
    int r = k2 / (16 * D_HID);
    int t = k2 - r * (16 * D_HID);
    int n = t >> 6, k = t & 63;
    W2Tb[k2] = (n < D_OUT) ? f2bf(W2[(r * D_HID + k) * D_OUT + n]) : (u16)0;
  } else if (idx < T3) {
    int k2 = idx - T2;
    int j = k2 >> 7, d = k2 & 127;
    loop1Tb[k2] = f2bf(loop1[d * D_HID + j]);
  }
}

// ---- histograms ----
__global__ __launch_bounds__(256) void k_zero_all(int* __restrict__ hist_rel,
                                                  int* __restrict__ hist_dst){
  int i = blockIdx.x * 256 + threadIdx.x;
  if (i < N_NODES) hist_dst[i] = 0;
  if (i < N_RELS)  hist_rel[i] = 0;
}

__global__ __launch_bounds__(256) void k_hist_rel(const int* __restrict__ et, int* __restrict__ hist){
  __shared__ int lh[N_RELS];
  int tid = threadIdx.x;
  if (tid < N_RELS) lh[tid] = 0;
  __syncthreads();
  int e = blockIdx.x * 256 + tid;
  if (e < N_EDGES) atomicAdd(&lh[et[e]], 1);
  __syncthreads();
  if (tid < N_RELS && lh[tid]) atomicAdd(&hist[tid], lh[tid]);
}

__global__ __launch_bounds__(256) void k_hist_dst(const int* __restrict__ dst, int* __restrict__ hist){
  int e = blockIdx.x * 256 + threadIdx.x;
  if (e < N_EDGES) atomicAdd(&hist[dst[e]], 1);
}

// rel scan: offs[20], toff[20] (tiles of 128), cursor_rel init
__global__ void k_scan_rel(const int* __restrict__ hist, int* __restrict__ offs,
                           int* __restrict__ toff, int* __restrict__ cursor){
  if (threadIdx.x == 0) {
    int acc = 0, tacc = 0;
    offs[0] = 0; toff[0] = 0;
    for (int r = 0; r < N_RELS; ++r) {
      cursor[r] = acc;
      int c = hist[r];
      acc += c;                offs[r + 1] = acc;
      tacc += (c + 127) >> 7;  toff[r + 1] = tacc;
    }
  }
}

// dst scan (one block): dcsr[50001] exclusive prefix; cursor_dst = copy
__global__ __launch_bounds__(256) void k_scan_dst(const int* __restrict__ hist,
                                                  int* __restrict__ dcsr,
                                                  int* __restrict__ cursor){
  __shared__ int wsum[4];
  int tid = threadIdx.x, lane = tid & 63, w = tid >> 6;
  const int CH = 196;                       // 196*256 = 50176 >= 50000
  int start = tid * CH;
  int s = 0;
  for (int i = 0; i < CH; ++i) { int idx = start + i; if (idx < N_NODES) s += hist[idx]; }
  int v = s;
  for (int o = 1; o < 64; o <<= 1) { int u = __shfl_up(v, o); if (lane >= o) v += u; }
  if (lane == 63) wsum[w] = v;
  __syncthreads();
  int woff = 0;
  for (int i = 0; i < w; ++i) woff += wsum[i];
  int run = woff + v - s;                   // exclusive prefix of this chunk
  for (int i = 0; i < CH; ++i) {
    int idx = start + i;
    if (idx < N_NODES) { dcsr[idx] = run; cursor[idx] = run; run += hist[idx]; }
  }
  if (tid == 255) dcsr[N_NODES] = run;      // = N_EDGES
}

__global__ __launch_bounds__(256) void k_scatter_rel(const int* __restrict__ et,
                                                     int* __restrict__ cursor,
                                                     int* __restrict__ perm){
  __shared__ int lh[N_RELS], base[N_RELS];
  int tid = threadIdx.x;
  if (tid < N_RELS) lh[tid] = 0;
  __syncthreads();
  int e = blockIdx.x * 256 + tid;
  int r = 0, my = 0;
  bool valid = e < N_EDGES;
  if (valid) { r = et[e]; my = atomicAdd(&lh[r], 1); }
  __syncthreads();
  if (tid < N_RELS && lh[tid]) base[tid] = atomicAdd(&cursor[tid], lh[tid]);
  __syncthreads();
  if (valid) perm[base[r] + my] = e;
}

// Self-loop layer 1: agg1f[64-node tile] = feat @ loop1 + b1 (fp32, full init)
__global__ __launch_bounds__(256) void k_selfloop1_mfma(
    const u16* __restrict__ featb, const u16* __restrict__ loop1Tb,
    const float* __restrict__ b1, float* __restrict__ agg1f){
  __shared__ __align__(16) u16 Als[64][136];
  __shared__ __align__(16) u16 Bls[64][136];
  int tid = threadIdx.x;
  int base = blockIdx.x * 64;
  { int j = tid >> 2, seg = tid & 3;
    const uint4* g = (const uint4*)(loop1Tb + j * 128) + seg * 4;
    uint4* d = (uint4*)&Bls[j][seg * 32];
    d[0] = g[0]; d[1] = g[1]; d[2] = g[2]; d[3] = g[3]; }
  { int i = tid >> 2, seg = tid & 3;
    int n = base + i; if (n >= N_NODES) n = N_NODES - 1;
    const uint4* g = (const uint4*)(featb + (size_t)n * D_IN) + seg * 4;
    uint4* d = (uint4*)&Als[i][seg * 32];
    d[0] = g[0]; d[1] = g[1]; d[2] = g[2]; d[3] = g[3]; }
  __syncthreads();

  int w = tid >> 6, lane = tid & 63;
  int r16 = lane & 15, c4 = lane >> 4;
  sfrag aF[4];
  #pragma unroll
  for (int kk = 0; kk < 4; ++kk)
    aF[kk] = *(const sfrag*)&Als[w * 16 + r16][kk * 32 + c4 * 8];
  #pragma unroll
  for (int ct = 0; ct < 4; ++ct) {
    f32x4 acc = {0.f, 0.f, 0.f, 0.f};
    #pragma unroll
    for (int kk = 0; kk < 4; ++kk) {
      sfrag bF = *(const sfrag*)&Bls[ct * 16 + r16][kk * 32 + c4 * 8];
      acc = __builtin_amdgcn_mfma_f32_16x16x32_bf16(aF[kk], bF, acc, 0, 0, 0);
    }
    int col = ct * 16 + r16;
    float bias = b1[col];
    #pragma unroll
    for (int reg = 0; reg < 4; ++reg) {
      int row = base + w * 16 + c4 * 4 + reg;
      if (row < N_NODES) agg1f[(size_t)row * D_HID + col] = acc[reg] + bias;
    }
  }
}

// Layer-1 edge messages: 128-edge rel-pure tile, K=128 bf16 MFMA,
// messages -> LDS fp32 -> bf16 rows stored at dst-sorted positions. NO agg atomics.
__global__ __launch_bounds__(256) void k_edge1_mfma(
    const u16* __restrict__ featb, const u16* __restrict__ W1Tb,
    const int* __restrict__ src, const int* __restrict__ dst,
    const int* __restrict__ perm, const int* __restrict__ offs,
    const int* __restrict__ toff, const int* __restrict__ dcsr,
    int* __restrict__ cursor, u16* __restrict__ msgbuf){
  __shared__ __align__(16) u16 Als[128][136];   // 34816 B; overlaid by msg fp32 [128][68] (same 272 B stride)
  __shared__ __align__(16) u16 Bls[64][136];    // 17408 B
  __shared__ int posIds[128];
  int tid = threadIdx.x, lane = tid & 63, w = tid >> 6;

  // ballot meta resolve: rel = #{r : b >= toff[r+1]}
  int b = blockIdx.x;
  unsigned long long mm = __ballot((lane < N_RELS) && (b >= toff[lane + 1]));
  int rel = __popcll(mm);
  if (rel >= N_RELS) return;                    // uniform across block
  int ts = offs[rel] + ((b - toff[rel]) << 7);
  int vc = offs[rel + 1] - ts; if (vc > 128) vc = 128;

  { // B tile: W1Tb[rel], 64 x 128 bf16 (16 KB)
    int j = tid >> 2, seg = tid & 3;
    const uint4* g = (const uint4*)(W1Tb + ((size_t)rel * 64 + j) * 128) + seg * 4;
    uint4* d = (uint4*)&Bls[j][seg * 32];
    d[0] = g[0]; d[1] = g[1]; d[2] = g[2]; d[3] = g[3];
  }
  // A tile: 128 rows x 256 B, 2 passes, 4 threads/row
  #pragma unroll
  for (int p = 0; p < 2; ++p) {
    int i = p * 64 + (tid >> 2), seg = tid & 3;
    if (i < vc) {
      int e = perm[ts + i];
      if (seg == 0) posIds[i] = atomicAdd(&cursor[dst[e]], 1);  // absolute msg row
      const uint4* g = (const uint4*)(featb + (size_t)src[e] * D_IN) + seg * 4;
      uint4* d = (uint4*)&Als[i][seg * 32];
      d[0] = g[0]; d[1] = g[1]; d[2] = g[2]; d[3] = g[3];
    } else if (seg == 0) posIds[i] = -1;        // pad row: A garbage OK (row-local, discarded)
  }
  __syncthreads();

  int r16 = lane & 15, c4 = lane >> 4;
  // wave w owns rows [w*32, w*32+32): 2 m-tiles
  sfrag aF[2][4];
  #pragma unroll
  for (int mt = 0; mt < 2; ++mt)
    #pragma unroll
    for (int kk = 0; kk < 4; ++kk)
      aF[mt][kk] = *(const sfrag*)&Als[w * 32 + mt * 16 + r16][kk * 32 + c4 * 8];
  f32x4 accAll[2][4];
  #pragma unroll
  for (int ct = 0; ct < 4; ++ct) {
    sfrag bF[4];
    #pragma unroll
    for (int kk = 0; kk < 4; ++kk)
      bF[kk] = *(const sfrag*)&Bls[ct * 16 + r16][kk * 32 + c4 * 8];
    #pragma unroll
    for (int mt = 0; mt < 2; ++mt) {
      f32x4 acc = {0.f, 0.f, 0.f, 0.f};
      #pragma unroll
      for (int kk = 0; kk < 4; ++kk)
        acc = __builtin_amdgcn_mfma_f32_16x16x32_bf16(aF[mt][kk], bF[kk], acc, 0, 0, 0);
      accAll[mt][ct] = acc;
    }
  }
  // msg overlay writes are wave-private (same rows the wave just read its frags from)
  float* msg = (float*)&Als[0][0];              // stride 68 floats == 272 B == Als row
  #pragma unroll
  for (int mt = 0; mt < 2; ++mt)
    #pragma unroll
    for (int ct = 0; ct < 4; ++ct) {
      int col = ct * 16 + r16;
      #pragma unroll
      for (int reg = 0; reg < 4; ++reg) {
        int row = w * 32 + mt * 16 + c4 * 4 + reg;   // D: col=lane&15, row=(lane>>4)*4+reg
        msg[row * 68 + col] = accAll[mt][ct][reg];
      }
    }
  __syncthreads();
  // write-out: thread t -> (row, half), 64 B bf16 per thread, coalesced within row
  { int row = tid >> 1, half = tid & 1;
    int pos = posIds[row];
    if (pos >= 0) {
      const float* mr = msg + row * 68 + half * 32;
      u32 pk[16];
      #pragma unroll
      for (int q = 0; q < 16; ++q)
        pk[q] = (u32)f2bf(mr[2 * q]) | ((u32)f2bf(mr[2 * q + 1]) << 16);
      uint4* d = (uint4*)(msgbuf + (size_t)pos * D_HID + half * 32);
      d[0] = *(uint4*)&pk[0];  d[1] = *(uint4*)&pk[4];
      d[2] = *(uint4*)&pk[8];  d[3] = *(uint4*)&pk[12];
    } }
}

// CSR aggregation: h1b[n] = bf16(relu(sum of msg rows + agg1f[n])). Full init of h1b.
__global__ __launch_bounds__(256) void k_agg(const u16* __restrict__ msgbuf,
                                             const int* __restrict__ dcsr,
                                             const float* __restrict__ agg1f,
                                             u16* __restrict__ h1b){
  int wv = threadIdx.x >> 6, lane = threadIdx.x & 63;
  int n = blockIdx.x * 4 + wv;
  int s = dcsr[n], epos = dcsr[n + 1];
  int h = lane >> 5, c = lane & 31;
  float a0 = 0.f, a1 = 0.f;
  for (int i = s + h; i < epos; i += 2) {
    u32 v = ((const u32*)msgbuf)[(size_t)i * 32 + c];
    a0 += bf2f((u16)(v & 0xffffu));
    a1 += bf2f((u16)(v >> 16));
  }
  a0 += __shfl_down(a0, 32);
  a1 += __shfl_down(a1, 32);
  if (h == 0) {
    float2 sl = ((const float2*)(agg1f + (size_t)n * D_HID))[c];
    float v0 = a0 + sl.x, v1 = a1 + sl.y;
    v0 = v0 > 0.f ? v0 : 0.f;
    v1 = v1 > 0.f ? v1 : 0.f;
    ((u32*)h1b)[n * 32 + c] = (u32)f2bf(v0) | ((u32)f2bf(v1) << 16);
  }
}

// out[n,k] = h1[n,:] @ loop2[:,k] + b2[k]  (full init of out)
__global__ __launch_bounds__(256) void k_self2(const u16* __restrict__ h1b,
                                               const float* __restrict__ loop2,
                                               const float* __restrict__ b2,
                                               float* __restrict__ out){
  int wv = threadIdx.x >> 6, lane = threadIdx.x & 63;
  int n = blockIdx.x * 4 + wv;
  float p0 = 0.f, p1 = 0.f;
  if (lane < 32) {
    u32 v = ((const u32*)h1b)[n * 32 + lane];
    float h0 = bf2f((u16)(v & 0xffffu));
    float h1v = bf2f((u16)(v >> 16));
    float2 w0 = ((const float2*)loop2)[2 * lane];
    float2 w1 = ((const float2*)loop2)[2 * lane + 1];
    p0 = h0 * w0.x + h1v * w1.x;
    p1 = h0 * w0.y + h1v * w1.y;
  }
  for (int off = 32; off; off >>= 1) {
    p0 += __shfl_down(p0, off);
    p1 += __shfl_down(p1, off);
  }
  if (lane == 0) {
    out[n * 2]     = p0 + b2[0];
    out[n * 2 + 1] = p1 + b2[1];
  }
}

// Layer-2 edge messages: 128-edge rel-pure tiles, K=64 bf16 MFMA, cheap 2-col atomics.
__global__ __launch_bounds__(256) void k_edge2_mfma(
    const u16* __restrict__ h1b, const u16* __restrict__ W2Tb,
    const int* __restrict__ src, const int* __restrict__ dst,
    const int* __restrict__ perm, const int* __restrict__ offs,
    const int* __restrict__ toff, float* __restrict__ out){
  __shared__ __align__(16) u16 Als[128][72];
  __shared__ __align__(16) u16 Bls[16][72];
  __shared__ int dstIds[128];
  int tid = threadIdx.x, lane = tid & 63, w = tid >> 6;

  int b = blockIdx.x;
  unsigned long long mm = __ballot((lane < N_RELS) && (b >= toff[lane + 1]));
  int rel = __popcll(mm);
  if (rel >= N_RELS) return;
  int ts = offs[rel] + ((b - toff[rel]) << 7);
  int vc = offs[rel + 1] - ts; if (vc > 128) vc = 128;

  if (tid < 128) {   // B tile: 16 x 64 bf16 = 128 uint4
    ((uint4*)&Bls[tid >> 3][0])[tid & 7] = ((const uint4*)(W2Tb + (size_t)rel * 16 * 64))[tid];
  }
  { // A: 128 rows x 128 B, 2 threads/row
    int i = tid >> 1, half = tid & 1;
    if (i < vc) {
      int e = perm[ts + i];
      if (half == 0) dstIds[i] = dst[e];
      const uint4* g = (const uint4*)(h1b + (size_t)src[e] * D_HID) + half * 4;
      uint4* d = (uint4*)&Als[i][half * 32];
      d[0] = g[0]; d[1] = g[1]; d[2] = g[2]; d[3] = g[3];
    } else if (half == 0) dstIds[i] = -1;
  }
  __syncthreads();

  int r16 = lane & 15, c4 = lane >> 4;
  #pragma unroll
  for (int mt = 0; mt < 2; ++mt) {
    f32x4 acc = {0.f, 0.f, 0.f, 0.f};
    #pragma unroll
    for (int kk = 0; kk < 2; ++kk) {
      sfrag aF = *(const sfrag*)&Als[w * 32 + mt * 16 + r16][kk * 32 + c4 * 8];
      sfrag bF = *(const sfrag*)&Bls[r16][kk * 32 + c4 * 8];
      acc = __builtin_amdgcn_mfma_f32_16x16x32_bf16(aF, bF, acc, 0, 0, 0);
    }
    if (r16 < D_OUT) {
      #pragma unroll
      for (int reg = 0; reg < 4; ++reg) {
        int row = w * 32 + mt * 16 + c4 * 4 + reg;
        int dn = dstIds[row];
        if (dn >= 0) atomicAdd(&out[dn * D_OUT + r16], acc[reg]);
      }
    }
  }
}

extern "C" void kernel_launch(void* const* d_in, const int* in_sizes, int n_in,
                              void* d_out, int out_size, void* d_ws, size_t ws_size,
                              hipStream_t stream){
  const float* feat  = (const float*)d_in[0];
  const float* W1    = (const float*)d_in[1];
  const float* loop1 = (const float*)d_in[2];
  const float* b1    = (const float*)d_in[3];
  const float* W2    = (const float*)d_in[4];
  const float* loop2 = (const float*)d_in[5];
  const float* b2    = (const float*)d_in[6];
  const int* src     = (const int*)d_in[7];
  const int* dst     = (const int*)d_in[8];
  const int* et      = (const int*)d_in[9];
  float* out = (float*)d_out;

  // workspace layout (16B-aligned), ~112 MB total
  char* w = (char*)d_ws;
  u16*   W1Tb     = (u16*)(w);                   //  311296
  u16*   W2Tb     = (u16*)(w + 311296);          //   38912
  u16*   loop1Tb  = (u16*)(w + 350208);          //   16384
  int*   hist_rel = (int*)(w + 366592);
  int*   offs     = (int*)(w + 366720);
  int*   toff     = (int*)(w + 366848);
  int*   cur_rel  = (int*)(w + 366976);
  int*   hist_dst = (int*)(w + 367104);          //  200000
  int*   dcsr     = (int*)(w + 567104);          //  200016
  int*   cur_dst  = (int*)(w + 767120);          //  200000
  int*   perm     = (int*)(w + 967120);          // 2400000
  u16*   featb    = (u16*)(w + 3367120);         // 12.8 MB
  float* agg1f    = (float*)(w + 16167120);      // 12.8 MB
  u16*   h1b      = (u16*)(w + 28967120);        //  6.4 MB
  u16*   msgbuf   = (u16*)(w + 35367120);        // 76.8 MB -> 112167120

  const int MAX_TILES = (N_EDGES + 127) / 128 + N_RELS;   // 4707

  k_prep          <<<716,   256, 0, stream>>>(W1, loop1, W2, W1Tb, loop1Tb, W2Tb);
  k_featb         <<<12500, 256, 0, stream>>>(feat, featb);
  k_zero_all      <<<196,   256, 0, stream>>>(hist_rel, hist_dst);
  k_hist_rel      <<<2344,  256, 0, stream>>>(et, hist_rel);
  k_hist_dst      <<<2344,  256, 0, stream>>>(dst, hist_dst);
  k_scan_rel      <<<1,      64, 0, stream>>>(hist_rel, offs, toff, cur_rel);
  k_scan_dst      <<<1,     256, 0, stream>>>(hist_dst, dcsr, cur_dst);
  k_scatter_rel   <<<2344,  256, 0, stream>>>(et, cur_rel, perm);
  k_selfloop1_mfma<<<(N_NODES + 63) / 64, 256, 0, stream>>>(featb, loop1Tb, b1, agg1f);
  k_edge1_mfma    <<<MAX_TILES, 256, 0, stream>>>(featb, W1Tb, src, dst, perm, offs, toff,
                                                  dcsr, cur_dst, msgbuf);
  k_agg           <<<12500, 256, 0, stream>>>(msgbuf, dcsr, agg1f, h1b);
  k_self2         <<<12500, 256, 0, stream>>>(h1b, loop2, b2, out);
  k_edge2_mfma    <<<MAX_TILES, 256, 0, stream>>>(h1b, W2Tb, src, dst, perm, offs, toff, out);
}

// Round 7
// 355.783 us; speedup vs baseline: 1.3430x; 1.3430x over previous
//
#include <hip/hip_runtime.h>

#define N_NODES 50000
#define N_EDGES 600000
#define N_RELS  19
#define D_IN    128
#define D_HID   64
#define D_OUT   2

typedef unsigned short u16;
typedef unsigned int   u32;
typedef __attribute__((ext_vector_type(8))) short sfrag;   // 8 bf16 (4 VGPRs)
typedef __attribute__((ext_vector_type(4))) float f32x4;   // 4 fp32 acc

__device__ __forceinline__ u16 f2bf(float f){
  union { float f; u32 i; } v; v.f = f;
  u32 r = v.i + 0x7fffu + ((v.i >> 16) & 1u);  // RNE
  return (u16)(r >> 16);
}
__device__ __forceinline__ float bf2f(u16 u){
  union { u32 i; float f; } v; v.i = ((u32)u) << 16; return v.f;
}

// feat fp32 -> featb bf16 (packed u32 pairs)
__global__ __launch_bounds__(256) void k_featb(const float* __restrict__ feat,
                                               u16* __restrict__ featb){
  int i = blockIdx.x * 256 + threadIdx.x;
  float2 f = ((const float2*)feat)[i];
  ((u32*)featb)[i] = (u32)f2bf(f.x) | ((u32)f2bf(f.y) << 16);
}

// Weights: W1Tb [19][64][128], W2Tb [19][16][64] (cols>=2 zero), loop1Tb [64][128] (all bf16, B^T)
__global__ void k_prep(const float* __restrict__ W1, const float* __restrict__ loop1,
                       const float* __restrict__ W2,
                       u16* __restrict__ W1Tb, u16* __restrict__ loop1Tb,
                       u16* __restrict__ W2Tb){
  int idx = blockIdx.x * 256 + threadIdx.x;
  const int T1 = N_RELS * D_HID * D_IN;        // 155648
  const int T2 = T1 + N_RELS * 16 * D_HID;     // +19456
  const int T3 = T2 + D_HID * D_IN;            // +8192
  if (idx < T1) {
    int r = idx / (D_HID * D_IN);
    int t = idx - r * (D_HID * D_IN);
    int j = t >> 7, d = t & 127;
    W1Tb[idx] = f2bf(W1[(r * D_IN + d) * D_HID + j]);
  } else if (idx < T2) {
    int k2 = idx - T1;
    int r = k2 / (16 * D_HID);
    int t = k2 - r * (16 * D_HID);
    int n = t >> 6, k = t & 63;
    W2Tb[k2] = (n < D_OUT) ? f2bf(W2[(r * D_HID + k) * D_OUT + n]) : (u16)0;
  } else if (idx < T3) {
    int k2 = idx - T2;
    int j = k2 >> 7, d = k2 & 127;
    loop1Tb[k2] = f2bf(loop1[d * D_HID + j]);
  }
}

// ---- histograms ----
__global__ __launch_bounds__(256) void k_zero_all(int* __restrict__ hist_rel,
                                                  int* __restrict__ hist_dst){
  int i = blockIdx.x * 256 + threadIdx.x;
  if (i < N_NODES) hist_dst[i] = 0;
  if (i < N_RELS)  hist_rel[i] = 0;
}

__global__ __launch_bounds__(256) void k_hist_rel(const int* __restrict__ et, int* __restrict__ hist){
  __shared__ int lh[N_RELS];
  int tid = threadIdx.x;
  if (tid < N_RELS) lh[tid] = 0;
  __syncthreads();
  int e = blockIdx.x * 256 + tid;
  if (e < N_EDGES) atomicAdd(&lh[et[e]], 1);
  __syncthreads();
  if (tid < N_RELS && lh[tid]) atomicAdd(&hist[tid], lh[tid]);
}

__global__ __launch_bounds__(256) void k_hist_dst(const int* __restrict__ dst, int* __restrict__ hist){
  int e = blockIdx.x * 256 + threadIdx.x;
  if (e < N_EDGES) atomicAdd(&hist[dst[e]], 1);
}

// rel scan: offs[20], toff[20] (tiles of 128), cursor_rel init (19 elements -> 1 thread fine)
__global__ void k_scan_rel(const int* __restrict__ hist, int* __restrict__ offs,
                           int* __restrict__ toff, int* __restrict__ cursor){
  if (threadIdx.x == 0) {
    int acc = 0, tacc = 0;
    offs[0] = 0; toff[0] = 0;
    for (int r = 0; r < N_RELS; ++r) {
      cursor[r] = acc;
      int c = hist[r];
      acc += c;                offs[r + 1] = acc;
      tacc += (c + 127) >> 7;  toff[r + 1] = tacc;
    }
  }
}

// ---- hierarchical dst scan: 196 blocks x 256 ----
__global__ __launch_bounds__(256) void k_scan_dst1(const int* __restrict__ hist,
                                                   int* __restrict__ dcsr,
                                                   int* __restrict__ bsum){
  __shared__ int ws[4];
  int tid = threadIdx.x, lane = tid & 63, w = tid >> 6;
  int i = blockIdx.x * 256 + tid;
  int v = (i < N_NODES) ? hist[i] : 0;
  int x = v;
  #pragma unroll
  for (int o = 1; o < 64; o <<= 1) { int u = __shfl_up(x, o); if (lane >= o) x += u; }
  if (lane == 63) ws[w] = x;
  __syncthreads();
  int add = 0;
  for (int j = 0; j < w; ++j) add += ws[j];
  int excl = x - v + add;
  if (i < N_NODES) dcsr[i] = excl;
  if (tid == 255) bsum[blockIdx.x] = excl + v;   // block total
}

__global__ __launch_bounds__(256) void k_scan_dst2(int* __restrict__ bsum,
                                                   int* __restrict__ boff){
  __shared__ int ws[4];
  int tid = threadIdx.x, lane = tid & 63, w = tid >> 6;
  int v = (tid < 196) ? bsum[tid] : 0;
  int x = v;
  #pragma unroll
  for (int o = 1; o < 64; o <<= 1) { int u = __shfl_up(x, o); if (lane >= o) x += u; }
  if (lane == 63) ws[w] = x;
  __syncthreads();
  int add = 0;
  for (int j = 0; j < w; ++j) add += ws[j];
  if (tid < 196) boff[tid] = x - v + add;
}

__global__ __launch_bounds__(256) void k_scan_dst3(const int* __restrict__ boff,
                                                   int* __restrict__ dcsr,
                                                   int* __restrict__ cursor){
  int i = blockIdx.x * 256 + threadIdx.x;
  if (i < N_NODES) {
    int val = dcsr[i] + boff[blockIdx.x];
    dcsr[i] = val;
    cursor[i] = val;
  }
  if (i == 0) dcsr[N_NODES] = N_EDGES;
}

__global__ __launch_bounds__(256) void k_scatter_rel(const int* __restrict__ et,
                                                     int* __restrict__ cursor,
                                                     int* __restrict__ perm){
  __shared__ int lh[N_RELS], base[N_RELS];
  int tid = threadIdx.x;
  if (tid < N_RELS) lh[tid] = 0;
  __syncthreads();
  int e = blockIdx.x * 256 + tid;
  int r = 0, my = 0;
  bool valid = e < N_EDGES;
  if (valid) { r = et[e]; my = atomicAdd(&lh[r], 1); }
  __syncthreads();
  if (tid < N_RELS && lh[tid]) base[tid] = atomicAdd(&cursor[tid], lh[tid]);
  __syncthreads();
  if (valid) perm[base[r] + my] = e;
}

// Self-loop layer 1: agg1f[64-node tile] = feat @ loop1 + b1 (fp32, full init)
__global__ __launch_bounds__(256) void k_selfloop1_mfma(
    const u16* __restrict__ featb, const u16* __restrict__ loop1Tb,
    const float* __restrict__ b1, float* __restrict__ agg1f){
  __shared__ __align__(16) u16 Als[64][136];
  __shared__ __align__(16) u16 Bls[64][136];
  int tid = threadIdx.x;
  int base = blockIdx.x * 64;
  { int j = tid >> 2, seg = tid & 3;
    const uint4* g = (const uint4*)(loop1Tb + j * 128) + seg * 4;
    uint4* d = (uint4*)&Bls[j][seg * 32];
    d[0] = g[0]; d[1] = g[1]; d[2] = g[2]; d[3] = g[3]; }
  { int i = tid >> 2, seg = tid & 3;
    int n = base + i; if (n >= N_NODES) n = N_NODES - 1;
    const uint4* g = (const uint4*)(featb + (size_t)n * D_IN) + seg * 4;
    uint4* d = (uint4*)&Als[i][seg * 32];
    d[0] = g[0]; d[1] = g[1]; d[2] = g[2]; d[3] = g[3]; }
  __syncthreads();

  int w = tid >> 6, lane = tid & 63;
  int r16 = lane & 15, c4 = lane >> 4;
  sfrag aF[4];
  #pragma unroll
  for (int kk = 0; kk < 4; ++kk)
    aF[kk] = *(const sfrag*)&Als[w * 16 + r16][kk * 32 + c4 * 8];
  #pragma unroll
  for (int ct = 0; ct < 4; ++ct) {
    f32x4 acc = {0.f, 0.f, 0.f, 0.f};
    #pragma unroll
    for (int kk = 0; kk < 4; ++kk) {
      sfrag bF = *(const sfrag*)&Bls[ct * 16 + r16][kk * 32 + c4 * 8];
      acc = __builtin_amdgcn_mfma_f32_16x16x32_bf16(aF[kk], bF, acc, 0, 0, 0);
    }
    int col = ct * 16 + r16;
    float bias = b1[col];
    #pragma unroll
    for (int reg = 0; reg < 4; ++reg) {
      int row = base + w * 16 + c4 * 4 + reg;
      if (row < N_NODES) agg1f[(size_t)row * D_HID + col] = acc[reg] + bias;
    }
  }
}

// Layer-1 edge messages: 128-edge rel-pure tile, K=128 bf16 MFMA,
// messages -> LDS fp32 -> bf16 rows stored at dst-sorted positions. NO agg atomics.
__global__ __launch_bounds__(256) void k_edge1_mfma(
    const u16* __restrict__ featb, const u16* __restrict__ W1Tb,
    const int* __restrict__ src, const int* __restrict__ dst,
    const int* __restrict__ perm, const int* __restrict__ offs,
    const int* __restrict__ toff, const int* __restrict__ dcsr,
    int* __restrict__ cursor, u16* __restrict__ msgbuf){
  __shared__ __align__(16) u16 Als[128][136];   // 34816 B; overlaid by msg fp32 [128][68] (same 272 B stride)
  __shared__ __align__(16) u16 Bls[64][136];    // 17408 B
  __shared__ int posIds[128];
  int tid = threadIdx.x, lane = tid & 63, w = tid >> 6;

  // ballot meta resolve: rel = #{r : b >= toff[r+1]}
  int b = blockIdx.x;
  unsigned long long mm = __ballot((lane < N_RELS) && (b >= toff[lane + 1]));
  int rel = __popcll(mm);
  if (rel >= N_RELS) return;                    // uniform across block
  int ts = offs[rel] + ((b - toff[rel]) << 7);
  int vc = offs[rel + 1] - ts; if (vc > 128) vc = 128;

  { // B tile: W1Tb[rel], 64 x 128 bf16 (16 KB)
    int j = tid >> 2, seg = tid & 3;
    const uint4* g = (const uint4*)(W1Tb + ((size_t)rel * 64 + j) * 128) + seg * 4;
    uint4* d = (uint4*)&Bls[j][seg * 32];
    d[0] = g[0]; d[1] = g[1]; d[2] = g[2]; d[3] = g[3];
  }
  // A tile: 128 rows x 256 B, 2 passes, 4 threads/row
  #pragma unroll
  for (int p = 0; p < 2; ++p) {
    int i = p * 64 + (tid >> 2), seg = tid & 3;
    if (i < vc) {
      int e = perm[ts + i];
      if (seg == 0) posIds[i] = atomicAdd(&cursor[dst[e]], 1);  // absolute msg row
      const uint4* g = (const uint4*)(featb + (size_t)src[e] * D_IN) + seg * 4;
      uint4* d = (uint4*)&Als[i][seg * 32];
      d[0] = g[0]; d[1] = g[1]; d[2] = g[2]; d[3] = g[3];
    } else if (seg == 0) posIds[i] = -1;        // pad row: A garbage OK (row-local, discarded)
  }
  __syncthreads();

  int r16 = lane & 15, c4 = lane >> 4;
  // wave w owns rows [w*32, w*32+32): 2 m-tiles
  sfrag aF[2][4];
  #pragma unroll
  for (int mt = 0; mt < 2; ++mt)
    #pragma unroll
    for (int kk = 0; kk < 4; ++kk)
      aF[mt][kk] = *(const sfrag*)&Als[w * 32 + mt * 16 + r16][kk * 32 + c4 * 8];
  f32x4 accAll[2][4];
  #pragma unroll
  for (int ct = 0; ct < 4; ++ct) {
    sfrag bF[4];
    #pragma unroll
    for (int kk = 0; kk < 4; ++kk)
      bF[kk] = *(const sfrag*)&Bls[ct * 16 + r16][kk * 32 + c4 * 8];
    #pragma unroll
    for (int mt = 0; mt < 2; ++mt) {
      f32x4 acc = {0.f, 0.f, 0.f, 0.f};
      #pragma unroll
      for (int kk = 0; kk < 4; ++kk)
        acc = __builtin_amdgcn_mfma_f32_16x16x32_bf16(aF[mt][kk], bF[kk], acc, 0, 0, 0);
      accAll[mt][ct] = acc;
    }
  }
  // msg overlay writes are wave-private (same rows the wave just read its frags from)
  float* msg = (float*)&Als[0][0];              // stride 68 floats == 272 B == Als row
  #pragma unroll
  for (int mt = 0; mt < 2; ++mt)
    #pragma unroll
    for (int ct = 0; ct < 4; ++ct) {
      int col = ct * 16 + r16;
      #pragma unroll
      for (int reg = 0; reg < 4; ++reg) {
        int row = w * 32 + mt * 16 + c4 * 4 + reg;   // D: col=lane&15, row=(lane>>4)*4+reg
        msg[row * 68 + col] = accAll[mt][ct][reg];
      }
    }
  __syncthreads();
  // write-out: thread t -> (row, half), 64 B bf16 per thread, coalesced within row
  { int row = tid >> 1, half = tid & 1;
    int pos = posIds[row];
    if (pos >= 0) {
      const float* mr = msg + row * 68 + half * 32;
      u32 pk[16];
      #pragma unroll
      for (int q = 0; q < 16; ++q)
        pk[q] = (u32)f2bf(mr[2 * q]) | ((u32)f2bf(mr[2 * q + 1]) << 16);
      uint4* d = (uint4*)(msgbuf + (size_t)pos * D_HID + half * 32);
      d[0] = *(uint4*)&pk[0];  d[1] = *(uint4*)&pk[4];
      d[2] = *(uint4*)&pk[8];  d[3] = *(uint4*)&pk[12];
    } }
}

// CSR aggregation: h1b[n] = bf16(relu(sum of msg rows + agg1f[n])). Full init of h1b.
__global__ __launch_bounds__(256) void k_agg(const u16* __restrict__ msgbuf,
                                             const int* __restrict__ dcsr,
                                             const float* __restrict__ agg1f,
                                             u16* __restrict__ h1b){
  int wv = threadIdx.x >> 6, lane = threadIdx.x & 63;
  int n = blockIdx.x * 4 + wv;
  int s = dcsr[n], epos = dcsr[n + 1];
  int h = lane >> 5, c = lane & 31;
  float a0 = 0.f, a1 = 0.f;
  for (int i = s + h; i < epos; i += 2) {
    u32 v = ((const u32*)msgbuf)[(size_t)i * 32 + c];
    a0 += bf2f((u16)(v & 0xffffu));
    a1 += bf2f((u16)(v >> 16));
  }
  a0 += __shfl_down(a0, 32);
  a1 += __shfl_down(a1, 32);
  if (h == 0) {
    float2 sl = ((const float2*)(agg1f + (size_t)n * D_HID))[c];
    float v0 = a0 + sl.x, v1 = a1 + sl.y;
    v0 = v0 > 0.f ? v0 : 0.f;
    v1 = v1 > 0.f ? v1 : 0.f;
    ((u32*)h1b)[n * 32 + c] = (u32)f2bf(v0) | ((u32)f2bf(v1) << 16);
  }
}

// out[n,k] = h1[n,:] @ loop2[:,k] + b2[k]  (full init of out)
__global__ __launch_bounds__(256) void k_self2(const u16* __restrict__ h1b,
                                               const float* __restrict__ loop2,
                                               const float* __restrict__ b2,
                                               float* __restrict__ out){
  int wv = threadIdx.x >> 6, lane = threadIdx.x & 63;
  int n = blockIdx.x * 4 + wv;
  float p0 = 0.f, p1 = 0.f;
  if (lane < 32) {
    u32 v = ((const u32*)h1b)[n * 32 + lane];
    float h0 = bf2f((u16)(v & 0xffffu));
    float h1v = bf2f((u16)(v >> 16));
    float2 w0 = ((const float2*)loop2)[2 * lane];
    float2 w1 = ((const float2*)loop2)[2 * lane + 1];
    p0 = h0 * w0.x + h1v * w1.x;
    p1 = h0 * w0.y + h1v * w1.y;
  }
  for (int off = 32; off; off >>= 1) {
    p0 += __shfl_down(p0, off);
    p1 += __shfl_down(p1, off);
  }
  if (lane == 0) {
    out[n * 2]     = p0 + b2[0];
    out[n * 2 + 1] = p1 + b2[1];
  }
}

// Layer-2 edge messages: 128-edge rel-pure tiles, K=64 bf16 MFMA, cheap 2-col atomics.
__global__ __launch_bounds__(256) void k_edge2_mfma(
    const u16* __restrict__ h1b, const u16* __restrict__ W2Tb,
    const int* __restrict__ src, const int* __restrict__ dst,
    const int* __restrict__ perm, const int* __restrict__ offs,
    const int* __restrict__ toff, float* __restrict__ out){
  __shared__ __align__(16) u16 Als[128][72];
  __shared__ __align__(16) u16 Bls[16][72];
  __shared__ int dstIds[128];
  int tid = threadIdx.x, lane = tid & 63, w = tid >> 6;

  int b = blockIdx.x;
  unsigned long long mm = __ballot((lane < N_RELS) && (b >= toff[lane + 1]));
  int rel = __popcll(mm);
  if (rel >= N_RELS) return;
  int ts = offs[rel] + ((b - toff[rel]) << 7);
  int vc = offs[rel + 1] - ts; if (vc > 128) vc = 128;

  if (tid < 128) {   // B tile: 16 x 64 bf16 = 128 uint4
    ((uint4*)&Bls[tid >> 3][0])[tid & 7] = ((const uint4*)(W2Tb + (size_t)rel * 16 * 64))[tid];
  }
  { // A: 128 rows x 128 B, 2 threads/row
    int i = tid >> 1, half = tid & 1;
    if (i < vc) {
      int e = perm[ts + i];
      if (half == 0) dstIds[i] = dst[e];
      const uint4* g = (const uint4*)(h1b + (size_t)src[e] * D_HID) + half * 4;
      uint4* d = (uint4*)&Als[i][half * 32];
      d[0] = g[0]; d[1] = g[1]; d[2] = g[2]; d[3] = g[3];
    } else if (half == 0) dstIds[i] = -1;
  }
  __syncthreads();

  int r16 = lane & 15, c4 = lane >> 4;
  #pragma unroll
  for (int mt = 0; mt < 2; ++mt) {
    f32x4 acc = {0.f, 0.f, 0.f, 0.f};
    #pragma unroll
    for (int kk = 0; kk < 2; ++kk) {
      sfrag aF = *(const sfrag*)&Als[w * 32 + mt * 16 + r16][kk * 32 + c4 * 8];
      sfrag bF = *(const sfrag*)&Bls[r16][kk * 32 + c4 * 8];
      acc = __builtin_amdgcn_mfma_f32_16x16x32_bf16(aF, bF, acc, 0, 0, 0);
    }
    if (r16 < D_OUT) {
      #pragma unroll
      for (int reg = 0; reg < 4; ++reg) {
        int row = w * 32 + mt * 16 + c4 * 4 + reg;
        int dn = dstIds[row];
        if (dn >= 0) atomicAdd(&out[dn * D_OUT + r16], acc[reg]);
      }
    }
  }
}

extern "C" void kernel_launch(void* const* d_in, const int* in_sizes, int n_in,
                              void* d_out, int out_size, void* d_ws, size_t ws_size,
                              hipStream_t stream){
  const float* feat  = (const float*)d_in[0];
  const float* W1    = (const float*)d_in[1];
  const float* loop1 = (const float*)d_in[2];
  const float* b1    = (const float*)d_in[3];
  const float* W2    = (const float*)d_in[4];
  const float* loop2 = (const float*)d_in[5];
  const float* b2    = (const float*)d_in[6];
  const int* src     = (const int*)d_in[7];
  const int* dst     = (const int*)d_in[8];
  const int* et      = (const int*)d_in[9];
  float* out = (float*)d_out;

  // workspace layout (16B-aligned), ~112 MB total
  char* w = (char*)d_ws;
  u16*   W1Tb     = (u16*)(w);                   //  311296
  u16*   W2Tb     = (u16*)(w + 311296);          //   38912
  u16*   loop1Tb  = (u16*)(w + 350208);          //   16384
  int*   hist_rel = (int*)(w + 366592);
  int*   offs     = (int*)(w + 366720);
  int*   toff     = (int*)(w + 366848);
  int*   cur_rel  = (int*)(w + 366976);
  int*   bsum     = (int*)(w + 367104);          //  784 B (196 ints) -> slot 1024
  int*   boff     = (int*)(w + 368128);          //  784 B -> slot 1024
  int*   hist_dst = (int*)(w + 369152);          //  200000
  int*   dcsr     = (int*)(w + 569152);          //  200016
  int*   cur_dst  = (int*)(w + 769168);          //  200000
  int*   perm     = (int*)(w + 969168);          // 2400000
  u16*   featb    = (u16*)(w + 3369168);         // 12.8 MB
  float* agg1f    = (float*)(w + 16169168);      // 12.8 MB
  u16*   h1b      = (u16*)(w + 28969168);        //  6.4 MB
  u16*   msgbuf   = (u16*)(w + 35369168);        // 76.8 MB -> 112169168

  const int MAX_TILES = (N_EDGES + 127) / 128 + N_RELS;   // 4707

  k_prep          <<<716,   256, 0, stream>>>(W1, loop1, W2, W1Tb, loop1Tb, W2Tb);
  k_featb         <<<12500, 256, 0, stream>>>(feat, featb);
  k_zero_all      <<<196,   256, 0, stream>>>(hist_rel, hist_dst);
  k_hist_rel      <<<2344,  256, 0, stream>>>(et, hist_rel);
  k_hist_dst      <<<2344,  256, 0, stream>>>(dst, hist_dst);
  k_scan_rel      <<<1,      64, 0, stream>>>(hist_rel, offs, toff, cur_rel);
  k_scan_dst1     <<<196,   256, 0, stream>>>(hist_dst, dcsr, bsum);
  k_scan_dst2     <<<1,     256, 0, stream>>>(bsum, boff);
  k_scan_dst3     <<<196,   256, 0, stream>>>(boff, dcsr, cur_dst);
  k_scatter_rel   <<<2344,  256, 0, stream>>>(et, cur_rel, perm);
  k_selfloop1_mfma<<<(N_NODES + 63) / 64, 256, 0, stream>>>(featb, loop1Tb, b1, agg1f);
  k_edge1_mfma    <<<MAX_TILES, 256, 0, stream>>>(featb, W1Tb, src, dst, perm, offs, toff,
                                                  dcsr, cur_dst, msgbuf);
  k_agg           <<<12500, 256, 0, stream>>>(msgbuf, dcsr, agg1f, h1b);
  k_self2         <<<12500, 256, 0, stream>>>(h1b, loop2, b2, out);
  k_edge2_mfma    <<<MAX_TILES, 256, 0, stream>>>(h1b, W2Tb, src, dst, perm, offs, toff, out);
}

// Round 8
// 338.219 us; speedup vs baseline: 1.4127x; 1.0519x over previous
//
#include <hip/hip_runtime.h>

#define N_NODES 50000
#define N_EDGES 600000
#define N_RELS  19
#define D_IN    128
#define D_HID   64
#define D_OUT   2

typedef unsigned short u16;
typedef unsigned int   u32;
typedef __attribute__((ext_vector_type(8))) short sfrag;   // 8 bf16 (4 VGPRs)
typedef __attribute__((ext_vector_type(4))) float f32x4;   // 4 fp32 acc

__device__ __forceinline__ u16 f2bf(float f){
  union { float f; u32 i; } v; v.f = f;
  u32 r = v.i + 0x7fffu + ((v.i >> 16) & 1u);  // RNE
  return (u16)(r >> 16);
}
__device__ __forceinline__ float bf2f(u16 u){
  union { u32 i; float f; } v; v.i = ((u32)u) << 16; return v.f;
}

// Weights: W1Tb [19][64][128], W2Tb [19][16][64] (cols>=2 zero), loop1Tb [64][128] (bf16, B^T).
// Also zeroes hist_rel (19 ints).
__global__ void k_prep(const float* __restrict__ W1, const float* __restrict__ loop1,
                       const float* __restrict__ W2,
                       u16* __restrict__ W1Tb, u16* __restrict__ loop1Tb,
                       u16* __restrict__ W2Tb, int* __restrict__ hist_rel){
  int idx = blockIdx.x * 256 + threadIdx.x;
  if (idx < N_RELS) hist_rel[idx] = 0;
  const int T1 = N_RELS * D_HID * D_IN;        // 155648
  const int T2 = T1 + N_RELS * 16 * D_HID;     // +19456
  const int T3 = T2 + D_HID * D_IN;            // +8192
  if (idx < T1) {
    int r = idx / (D_HID * D_IN);
    int t = idx - r * (D_HID * D_IN);
    int j = t >> 7, d = t & 127;
    W1Tb[idx] = f2bf(W1[(r * D_IN + d) * D_HID + j]);
  } else if (idx < T2) {
    int k2 = idx - T1;
    int r = k2 / (16 * D_HID);
    int t = k2 - r * (16 * D_HID);
    int n = t >> 6, k = t & 63;
    W2Tb[k2] = (n < D_OUT) ? f2bf(W2[(r * D_HID + k) * D_OUT + n]) : (u16)0;
  } else if (idx < T3) {
    int k2 = idx - T2;
    int j = k2 >> 7, d = k2 & 127;
    loop1Tb[k2] = f2bf(loop1[d * D_HID + j]);
  }
}

// Fused: feat->featb bf16 convert (3.2M u32), zero agg1b (1.6M u32), rel histogram.
__global__ __launch_bounds__(256) void k_fused_pre(const float* __restrict__ feat,
                                                   u16* __restrict__ featb,
                                                   u32* __restrict__ agg1b_z,
                                                   const int* __restrict__ et,
                                                   int* __restrict__ hist_rel){
  int i = blockIdx.x * 256 + threadIdx.x;
  if (i < (N_NODES * D_IN) / 2) {
    float2 f = ((const float2*)feat)[i];
    ((u32*)featb)[i] = (u32)f2bf(f.x) | ((u32)f2bf(f.y) << 16);
  }
  if (i < (N_NODES * D_HID) / 2) agg1b_z[i] = 0u;
  if (blockIdx.x < (N_EDGES + 255) / 256) {      // block-uniform branch
    __shared__ int lh[N_RELS];
    int tid = threadIdx.x;
    if (tid < N_RELS) lh[tid] = 0;
    __syncthreads();
    int e = blockIdx.x * 256 + tid;
    if (e < N_EDGES) atomicAdd(&lh[et[e]], 1);
    __syncthreads();
    if (tid < N_RELS && lh[tid]) atomicAdd(&hist_rel[tid], lh[tid]);
  }
}

// rel scan: offs[20], toff[20] (tiles of 128), cursor init
__global__ void k_scan_rel(const int* __restrict__ hist, int* __restrict__ offs,
                           int* __restrict__ toff, int* __restrict__ cursor){
  if (threadIdx.x == 0) {
    int acc = 0, tacc = 0;
    offs[0] = 0; toff[0] = 0;
    for (int r = 0; r < N_RELS; ++r) {
      cursor[r] = acc;
      int c = hist[r];
      acc += c;                offs[r + 1] = acc;
      tacc += (c + 127) >> 7;  toff[r + 1] = tacc;
    }
  }
}

__global__ __launch_bounds__(256) void k_scatter_rel(const int* __restrict__ et,
                                                     int* __restrict__ cursor,
                                                     int* __restrict__ perm){
  __shared__ int lh[N_RELS], base[N_RELS];
  int tid = threadIdx.x;
  if (tid < N_RELS) lh[tid] = 0;
  __syncthreads();
  int e = blockIdx.x * 256 + tid;
  int r = 0, my = 0;
  bool valid = e < N_EDGES;
  if (valid) { r = et[e]; my = atomicAdd(&lh[r], 1); }
  __syncthreads();
  if (tid < N_RELS && lh[tid]) base[tid] = atomicAdd(&cursor[tid], lh[tid]);
  __syncthreads();
  if (valid) perm[base[r] + my] = e;
}

// Self-loop layer 1: agg1f[64-node tile] = feat @ loop1 + b1 (fp32, full init)
__global__ __launch_bounds__(256) void k_selfloop1_mfma(
    const u16* __restrict__ featb, const u16* __restrict__ loop1Tb,
    const float* __restrict__ b1, float* __restrict__ agg1f){
  __shared__ __align__(16) u16 Als[64][136];
  __shared__ __align__(16) u16 Bls[64][136];
  int tid = threadIdx.x;
  int base = blockIdx.x * 64;
  { int j = tid >> 2, seg = tid & 3;
    const uint4* g = (const uint4*)(loop1Tb + j * 128) + seg * 4;
    uint4* d = (uint4*)&Bls[j][seg * 32];
    d[0] = g[0]; d[1] = g[1]; d[2] = g[2]; d[3] = g[3]; }
  { int i = tid >> 2, seg = tid & 3;
    int n = base + i; if (n >= N_NODES) n = N_NODES - 1;
    const uint4* g = (const uint4*)(featb + (size_t)n * D_IN) + seg * 4;
    uint4* d = (uint4*)&Als[i][seg * 32];
    d[0] = g[0]; d[1] = g[1]; d[2] = g[2]; d[3] = g[3]; }
  __syncthreads();

  int w = tid >> 6, lane = tid & 63;
  int r16 = lane & 15, c4 = lane >> 4;
  sfrag aF[4];
  #pragma unroll
  for (int kk = 0; kk < 4; ++kk)
    aF[kk] = *(const sfrag*)&Als[w * 16 + r16][kk * 32 + c4 * 8];
  #pragma unroll
  for (int ct = 0; ct < 4; ++ct) {
    f32x4 acc = {0.f, 0.f, 0.f, 0.f};
    #pragma unroll
    for (int kk = 0; kk < 4; ++kk) {
      sfrag bF = *(const sfrag*)&Bls[ct * 16 + r16][kk * 32 + c4 * 8];
      acc = __builtin_amdgcn_mfma_f32_16x16x32_bf16(aF[kk], bF, acc, 0, 0, 0);
    }
    int col = ct * 16 + r16;
    float bias = b1[col];
    #pragma unroll
    for (int reg = 0; reg < 4; ++reg) {
      int row = base + w * 16 + c4 * 4 + reg;
      if (row < N_NODES) agg1f[(size_t)row * D_HID + col] = acc[reg] + bias;
    }
  }
}

// Layer-1 edge messages: 128-edge rel-pure tile, K=128 bf16 MFMA,
// scatter via packed bf16x2 atomics into agg1b (no msgbuf, no dst sort).
__global__ __launch_bounds__(256) void k_edge1_mfma(
    const u16* __restrict__ featb, const u16* __restrict__ W1Tb,
    const int* __restrict__ src, const int* __restrict__ dst,
    const int* __restrict__ perm, const int* __restrict__ offs,
    const int* __restrict__ toff, u16* __restrict__ agg1b){
  __shared__ __align__(16) u16 Als[128][136];   // 34816 B
  __shared__ __align__(16) u16 Bls[64][136];    // 17408 B
  __shared__ int dstIds[128];
  int tid = threadIdx.x, lane = tid & 63, w = tid >> 6;

  // ballot meta resolve: rel = #{r : b >= toff[r+1]}
  int b = blockIdx.x;
  unsigned long long mm = __ballot((lane < N_RELS) && (b >= toff[lane + 1]));
  int rel = __popcll(mm);
  if (rel >= N_RELS) return;                    // uniform across block
  int ts = offs[rel] + ((b - toff[rel]) << 7);
  int vc = offs[rel + 1] - ts; if (vc > 128) vc = 128;

  { // B tile: W1Tb[rel], 64 x 128 bf16 (16 KB)
    int j = tid >> 2, seg = tid & 3;
    const uint4* g = (const uint4*)(W1Tb + ((size_t)rel * 64 + j) * 128) + seg * 4;
    uint4* d = (uint4*)&Bls[j][seg * 32];
    d[0] = g[0]; d[1] = g[1]; d[2] = g[2]; d[3] = g[3];
  }
  // A tile: 128 rows x 256 B, 2 passes, 4 threads/row
  #pragma unroll
  for (int p = 0; p < 2; ++p) {
    int i = p * 64 + (tid >> 2), seg = tid & 3;
    if (i < vc) {
      int e = perm[ts + i];
      if (seg == 0) dstIds[i] = dst[e];
      const uint4* g = (const uint4*)(featb + (size_t)src[e] * D_IN) + seg * 4;
      uint4* d = (uint4*)&Als[i][seg * 32];
      d[0] = g[0]; d[1] = g[1]; d[2] = g[2]; d[3] = g[3];
    } else if (seg == 0) dstIds[i] = -1;        // pad row: A garbage OK (guarded at scatter)
  }
  __syncthreads();

  int r16 = lane & 15, c4 = lane >> 4;
  sfrag aF[2][4];
  #pragma unroll
  for (int mt = 0; mt < 2; ++mt)
    #pragma unroll
    for (int kk = 0; kk < 4; ++kk)
      aF[mt][kk] = *(const sfrag*)&Als[w * 32 + mt * 16 + r16][kk * 32 + c4 * 8];
  f32x4 accAll[2][4];
  #pragma unroll
  for (int ct = 0; ct < 4; ++ct) {
    sfrag bF[4];
    #pragma unroll
    for (int kk = 0; kk < 4; ++kk)
      bF[kk] = *(const sfrag*)&Bls[ct * 16 + r16][kk * 32 + c4 * 8];
    #pragma unroll
    for (int mt = 0; mt < 2; ++mt) {
      f32x4 acc = {0.f, 0.f, 0.f, 0.f};
      #pragma unroll
      for (int kk = 0; kk < 4; ++kk)
        acc = __builtin_amdgcn_mfma_f32_16x16x32_bf16(aF[mt][kk], bF[kk], acc, 0, 0, 0);
      accAll[mt][ct] = acc;
    }
  }
  // scatter: pack col pairs (adjacent r16 lanes), even lane issues one 4B pk atomic
  #pragma unroll
  for (int mt = 0; mt < 2; ++mt)
    #pragma unroll
    for (int ct = 0; ct < 4; ++ct) {
      int col = ct * 16 + r16;                  // D: col=lane&15, row=(lane>>4)*4+reg
      #pragma unroll
      for (int reg = 0; reg < 4; ++reg) {
        float other = __shfl_xor(accAll[mt][ct][reg], 1);
        if (!(r16 & 1)) {
          int row = w * 32 + mt * 16 + c4 * 4 + reg;
          int dn = dstIds[row];
          if (dn >= 0) {
            u32 p = (u32)f2bf(accAll[mt][ct][reg]) | ((u32)f2bf(other) << 16);
            unsigned long long a = (unsigned long long)(agg1b + (size_t)dn * D_HID + col);
            asm volatile("global_atomic_pk_add_bf16 %0, %1, off"
                         :: "v"(a), "v"(p) : "memory");
          }
        }
      }
    }
  asm volatile("s_waitcnt vmcnt(0)" ::: "memory");  // drain fire-and-forget atomics
}

// Fused epilogue of layer 1 + self-loop of layer 2:
// h1 = relu(agg1b + agg1f) -> h1b (full init); out[n,:] = h1 @ loop2 + b2 (full init).
__global__ __launch_bounds__(256) void k_agg_relu_self2(
    const u16* __restrict__ agg1b, const float* __restrict__ agg1f,
    const float* __restrict__ loop2, const float* __restrict__ b2,
    u16* __restrict__ h1b, float* __restrict__ out){
  int wv = threadIdx.x >> 6, lane = threadIdx.x & 63;
  int n = blockIdx.x * 4 + wv;
  float p0 = 0.f, p1 = 0.f;
  if (lane < 32) {
    u32 m = ((const u32*)agg1b)[(size_t)n * 32 + lane];
    float2 sl = ((const float2*)(agg1f + (size_t)n * D_HID))[lane];
    float v0 = bf2f((u16)(m & 0xffffu)) + sl.x;
    float v1 = bf2f((u16)(m >> 16)) + sl.y;
    v0 = v0 > 0.f ? v0 : 0.f;
    v1 = v1 > 0.f ? v1 : 0.f;
    ((u32*)h1b)[(size_t)n * 32 + lane] = (u32)f2bf(v0) | ((u32)f2bf(v1) << 16);
    float2 w0 = ((const float2*)loop2)[2 * lane];       // loop2 row 2*lane
    float2 w1 = ((const float2*)loop2)[2 * lane + 1];   // loop2 row 2*lane+1
    p0 = v0 * w0.x + v1 * w1.x;
    p1 = v0 * w0.y + v1 * w1.y;
  }
  #pragma unroll
  for (int off = 16; off; off >>= 1) {
    p0 += __shfl_down(p0, off);
    p1 += __shfl_down(p1, off);
  }
  if (lane == 0) {
    out[n * 2]     = p0 + b2[0];
    out[n * 2 + 1] = p1 + b2[1];
  }
}

// Layer-2 edge messages: 128-edge rel-pure tiles, K=64 bf16 MFMA, cheap 2-col atomics.
__global__ __launch_bounds__(256) void k_edge2_mfma(
    const u16* __restrict__ h1b, const u16* __restrict__ W2Tb,
    const int* __restrict__ src, const int* __restrict__ dst,
    const int* __restrict__ perm, const int* __restrict__ offs,
    const int* __restrict__ toff, float* __restrict__ out){
  __shared__ __align__(16) u16 Als[128][72];
  __shared__ __align__(16) u16 Bls[16][72];
  __shared__ int dstIds[128];
  int tid = threadIdx.x, lane = tid & 63, w = tid >> 6;

  int b = blockIdx.x;
  unsigned long long mm = __ballot((lane < N_RELS) && (b >= toff[lane + 1]));
  int rel = __popcll(mm);
  if (rel >= N_RELS) return;
  int ts = offs[rel] + ((b - toff[rel]) << 7);
  int vc = offs[rel + 1] - ts; if (vc > 128) vc = 128;

  if (tid < 128) {   // B tile: 16 x 64 bf16 = 128 uint4
    ((uint4*)&Bls[tid >> 3][0])[tid & 7] = ((const uint4*)(W2Tb + (size_t)rel * 16 * 64))[tid];
  }
  { // A: 128 rows x 128 B, 2 threads/row
    int i = tid >> 1, half = tid & 1;
    if (i < vc) {
      int e = perm[ts + i];
      if (half == 0) dstIds[i] = dst[e];
      const uint4* g = (const uint4*)(h1b + (size_t)src[e] * D_HID) + half * 4;
      uint4* d = (uint4*)&Als[i][half * 32];
      d[0] = g[0]; d[1] = g[1]; d[2] = g[2]; d[3] = g[3];
    } else if (half == 0) dstIds[i] = -1;
  }
  __syncthreads();

  int r16 = lane & 15, c4 = lane >> 4;
  #pragma unroll
  for (int mt = 0; mt < 2; ++mt) {
    f32x4 acc = {0.f, 0.f, 0.f, 0.f};
    #pragma unroll
    for (int kk = 0; kk < 2; ++kk) {
      sfrag aF = *(const sfrag*)&Als[w * 32 + mt * 16 + r16][kk * 32 + c4 * 8];
      sfrag bF = *(const sfrag*)&Bls[r16][kk * 32 + c4 * 8];
      acc = __builtin_amdgcn_mfma_f32_16x16x32_bf16(aF, bF, acc, 0, 0, 0);
    }
    if (r16 < D_OUT) {
      #pragma unroll
      for (int reg = 0; reg < 4; ++reg) {
        int row = w * 32 + mt * 16 + c4 * 4 + reg;
        int dn = dstIds[row];
        if (dn >= 0) atomicAdd(&out[dn * D_OUT + r16], acc[reg]);
      }
    }
  }
}

extern "C" void kernel_launch(void* const* d_in, const int* in_sizes, int n_in,
                              void* d_out, int out_size, void* d_ws, size_t ws_size,
                              hipStream_t stream){
  const float* feat  = (const float*)d_in[0];
  const float* W1    = (const float*)d_in[1];
  const float* loop1 = (const float*)d_in[2];
  const float* b1    = (const float*)d_in[3];
  const float* W2    = (const float*)d_in[4];
  const float* loop2 = (const float*)d_in[5];
  const float* b2    = (const float*)d_in[6];
  const int* src     = (const int*)d_in[7];
  const int* dst     = (const int*)d_in[8];
  const int* et      = (const int*)d_in[9];
  float* out = (float*)d_out;

  // workspace layout (16B-aligned), ~36 MB total
  char* w = (char*)d_ws;
  u16*   W1Tb     = (u16*)(w);                   //  311296
  u16*   W2Tb     = (u16*)(w + 311296);          //   38912
  u16*   loop1Tb  = (u16*)(w + 350208);          //   16384
  int*   hist_rel = (int*)(w + 366592);          //     128
  int*   offs     = (int*)(w + 366720);
  int*   toff     = (int*)(w + 366848);
  int*   cur_rel  = (int*)(w + 366976);
  int*   perm     = (int*)(w + 367104);          // 2400000 -> 2767104
  u16*   featb    = (u16*)(w + 2767104);         // 12.8 MB -> 15567104
  float* agg1f    = (float*)(w + 15567104);      // 12.8 MB -> 28367104
  u16*   agg1b    = (u16*)(w + 28367104);        //  6.4 MB -> 34767104
  u16*   h1b      = (u16*)(w + 34767104);        //  6.4 MB -> 41167104

  const int MAX_TILES = (N_EDGES + 127) / 128 + N_RELS;   // 4707

  k_prep          <<<716,   256, 0, stream>>>(W1, loop1, W2, W1Tb, loop1Tb, W2Tb, hist_rel);
  k_fused_pre     <<<12500, 256, 0, stream>>>(feat, featb, (u32*)agg1b, et, hist_rel);
  k_scan_rel      <<<1,      64, 0, stream>>>(hist_rel, offs, toff, cur_rel);
  k_scatter_rel   <<<2344,  256, 0, stream>>>(et, cur_rel, perm);
  k_selfloop1_mfma<<<(N_NODES + 63) / 64, 256, 0, stream>>>(featb, loop1Tb, b1, agg1f);
  k_edge1_mfma    <<<MAX_TILES, 256, 0, stream>>>(featb, W1Tb, src, dst, perm, offs, toff, agg1b);
  k_agg_relu_self2<<<12500, 256, 0, stream>>>(agg1b, agg1f, loop2, b2, h1b, out);
  k_edge2_mfma    <<<MAX_TILES, 256, 0, stream>>>(h1b, W2Tb, src, dst, perm, offs, toff, out);
}

// Round 9
// 329.458 us; speedup vs baseline: 1.4503x; 1.0266x over previous
//
#include <hip/hip_runtime.h>

#define N_NODES 50000
#define N_EDGES 600000
#define N_RELS  19
#define D_IN    128
#define D_HID   64
#define D_OUT   2

typedef unsigned short u16;
typedef unsigned int   u32;
typedef __attribute__((ext_vector_type(8))) short sfrag;   // 8 bf16 (4 VGPRs)
typedef __attribute__((ext_vector_type(4))) float f32x4;   // 4 fp32 acc

__device__ __forceinline__ u16 f2bf(float f){
  union { float f; u32 i; } v; v.f = f;
  u32 r = v.i + 0x7fffu + ((v.i >> 16) & 1u);  // RNE
  return (u16)(r >> 16);
}
__device__ __forceinline__ float bf2f(u16 u){
  union { u32 i; float f; } v; v.i = ((u32)u) << 16; return v.f;
}

// Weights: W1Tb [19][64][128], W2Tb [19][16][64] (cols>=2 zero), loop1Tb [64][128] (bf16, B^T).
// Also zeroes hist_rel (19) and hist_dst (50000).
__global__ void k_prep(const float* __restrict__ W1, const float* __restrict__ loop1,
                       const float* __restrict__ W2,
                       u16* __restrict__ W1Tb, u16* __restrict__ loop1Tb,
                       u16* __restrict__ W2Tb, int* __restrict__ hist_rel,
                       int* __restrict__ hist_dst){
  int idx = blockIdx.x * 256 + threadIdx.x;
  if (idx < N_RELS)  hist_rel[idx] = 0;
  if (idx < N_NODES) hist_dst[idx] = 0;
  const int T1 = N_RELS * D_HID * D_IN;        // 155648
  const int T2 = T1 + N_RELS * 16 * D_HID;     // +19456
  const int T3 = T2 + D_HID * D_IN;            // +8192 = 183296
  if (idx < T1) {
    int r = idx / (D_HID * D_IN);
    int t = idx - r * (D_HID * D_IN);
    int j = t >> 7, d = t & 127;
    W1Tb[idx] = f2bf(W1[(r * D_IN + d) * D_HID + j]);
  } else if (idx < T2) {
    int k2 = idx - T1;
    int r = k2 / (16 * D_HID);
    int t = k2 - r * (16 * D_HID);
    int n = t >> 6, k = t & 63;
    W2Tb[k2] = (n < D_OUT) ? f2bf(W2[(r * D_HID + k) * D_OUT + n]) : (u16)0;
  } else if (idx < T3) {
    int k2 = idx - T2;
    int j = k2 >> 7, d = k2 & 127;
    loop1Tb[k2] = f2bf(loop1[d * D_HID + j]);
  }
}

// Fused: feat->featb bf16 convert (3.2M u32), rel histogram, dst histogram.
__global__ __launch_bounds__(256) void k_fused_pre(const float* __restrict__ feat,
                                                   u16* __restrict__ featb,
                                                   const int* __restrict__ et,
                                                   const int* __restrict__ dst,
                                                   int* __restrict__ hist_rel,
                                                   int* __restrict__ hist_dst){
  int i = blockIdx.x * 256 + threadIdx.x;
  float2 f = ((const float2*)feat)[i];
  ((u32*)featb)[i] = (u32)f2bf(f.x) | ((u32)f2bf(f.y) << 16);
  if (blockIdx.x < (N_EDGES + 255) / 256) {      // block-uniform branch
    __shared__ int lh[N_RELS];
    int tid = threadIdx.x;
    if (tid < N_RELS) lh[tid] = 0;
    __syncthreads();
    int e = blockIdx.x * 256 + tid;
    if (e < N_EDGES) {
      atomicAdd(&lh[et[e]], 1);
      atomicAdd(&hist_dst[dst[e]], 1);
    }
    __syncthreads();
    if (tid < N_RELS && lh[tid]) atomicAdd(&hist_rel[tid], lh[tid]);
  }
}

// rel scan: offs[20], toff[20] (tiles of 128), cursor init
__global__ void k_scan_rel(const int* __restrict__ hist, int* __restrict__ offs,
                           int* __restrict__ toff, int* __restrict__ cursor){
  if (threadIdx.x == 0) {
    int acc = 0, tacc = 0;
    offs[0] = 0; toff[0] = 0;
    for (int r = 0; r < N_RELS; ++r) {
      cursor[r] = acc;
      int c = hist[r];
      acc += c;                offs[r + 1] = acc;
      tacc += (c + 127) >> 7;  toff[r + 1] = tacc;
    }
  }
}

// ---- hierarchical dst scan: 196 blocks x 256 ----
__global__ __launch_bounds__(256) void k_scan_dst1(const int* __restrict__ hist,
                                                   int* __restrict__ dcsr,
                                                   int* __restrict__ bsum){
  __shared__ int ws[4];
  int tid = threadIdx.x, lane = tid & 63, w = tid >> 6;
  int i = blockIdx.x * 256 + tid;
  int v = (i < N_NODES) ? hist[i] : 0;
  int x = v;
  #pragma unroll
  for (int o = 1; o < 64; o <<= 1) { int u = __shfl_up(x, o); if (lane >= o) x += u; }
  if (lane == 63) ws[w] = x;
  __syncthreads();
  int add = 0;
  for (int j = 0; j < w; ++j) add += ws[j];
  int excl = x - v + add;
  if (i < N_NODES) dcsr[i] = excl;
  if (tid == 255) bsum[blockIdx.x] = excl + v;   // block total
}

__global__ __launch_bounds__(256) void k_scan_dst2(int* __restrict__ bsum,
                                                   int* __restrict__ boff){
  __shared__ int ws[4];
  int tid = threadIdx.x, lane = tid & 63, w = tid >> 6;
  int v = (tid < 196) ? bsum[tid] : 0;
  int x = v;
  #pragma unroll
  for (int o = 1; o < 64; o <<= 1) { int u = __shfl_up(x, o); if (lane >= o) x += u; }
  if (lane == 63) ws[w] = x;
  __syncthreads();
  int add = 0;
  for (int j = 0; j < w; ++j) add += ws[j];
  if (tid < 196) boff[tid] = x - v + add;
}

__global__ __launch_bounds__(256) void k_scan_dst3(const int* __restrict__ boff,
                                                   int* __restrict__ dcsr,
                                                   int* __restrict__ cursor){
  int i = blockIdx.x * 256 + threadIdx.x;
  if (i < N_NODES) {
    int val = dcsr[i] + boff[blockIdx.x];
    dcsr[i] = val;
    cursor[i] = val;
  }
  if (i == 0) dcsr[N_NODES] = N_EDGES;
}

__global__ __launch_bounds__(256) void k_scatter_rel(const int* __restrict__ et,
                                                     int* __restrict__ cursor,
                                                     int* __restrict__ perm){
  __shared__ int lh[N_RELS], base[N_RELS];
  int tid = threadIdx.x;
  if (tid < N_RELS) lh[tid] = 0;
  __syncthreads();
  int e = blockIdx.x * 256 + tid;
  int r = 0, my = 0;
  bool valid = e < N_EDGES;
  if (valid) { r = et[e]; my = atomicAdd(&lh[r], 1); }
  __syncthreads();
  if (tid < N_RELS && lh[tid]) base[tid] = atomicAdd(&cursor[tid], lh[tid]);
  __syncthreads();
  if (valid) perm[base[r] + my] = e;
}

// Self-loop layer 1: agg1f[64-node tile] = feat @ loop1 + b1 (fp32, full init)
__global__ __launch_bounds__(256) void k_selfloop1_mfma(
    const u16* __restrict__ featb, const u16* __restrict__ loop1Tb,
    const float* __restrict__ b1, float* __restrict__ agg1f){
  __shared__ __align__(16) u16 Als[64][136];
  __shared__ __align__(16) u16 Bls[64][136];
  int tid = threadIdx.x;
  int base = blockIdx.x * 64;
  { int j = tid >> 2, seg = tid & 3;
    const uint4* g = (const uint4*)(loop1Tb + j * 128) + seg * 4;
    uint4* d = (uint4*)&Bls[j][seg * 32];
    d[0] = g[0]; d[1] = g[1]; d[2] = g[2]; d[3] = g[3]; }
  { int i = tid >> 2, seg = tid & 3;
    int n = base + i; if (n >= N_NODES) n = N_NODES - 1;
    const uint4* g = (const uint4*)(featb + (size_t)n * D_IN) + seg * 4;
    uint4* d = (uint4*)&Als[i][seg * 32];
    d[0] = g[0]; d[1] = g[1]; d[2] = g[2]; d[3] = g[3]; }
  __syncthreads();

  int w = tid >> 6, lane = tid & 63;
  int r16 = lane & 15, c4 = lane >> 4;
  sfrag aF[4];
  #pragma unroll
  for (int kk = 0; kk < 4; ++kk)
    aF[kk] = *(const sfrag*)&Als[w * 16 + r16][kk * 32 + c4 * 8];
  #pragma unroll
  for (int ct = 0; ct < 4; ++ct) {
    f32x4 acc = {0.f, 0.f, 0.f, 0.f};
    #pragma unroll
    for (int kk = 0; kk < 4; ++kk) {
      sfrag bF = *(const sfrag*)&Bls[ct * 16 + r16][kk * 32 + c4 * 8];
      acc = __builtin_amdgcn_mfma_f32_16x16x32_bf16(aF[kk], bF, acc, 0, 0, 0);
    }
    int col = ct * 16 + r16;
    float bias = b1[col];
    #pragma unroll
    for (int reg = 0; reg < 4; ++reg) {
      int row = base + w * 16 + c4 * 4 + reg;
      if (row < N_NODES) agg1f[(size_t)row * D_HID + col] = acc[reg] + bias;
    }
  }
}

// Layer-1 edge messages: 128-edge rel-pure tile, K=128 bf16 MFMA,
// messages -> LDS fp32 -> bf16 rows stored at dst-sorted positions. NO agg atomics.
__global__ __launch_bounds__(256) void k_edge1_mfma(
    const u16* __restrict__ featb, const u16* __restrict__ W1Tb,
    const int* __restrict__ src, const int* __restrict__ dst,
    const int* __restrict__ perm, const int* __restrict__ offs,
    const int* __restrict__ toff, const int* __restrict__ dcsr,
    int* __restrict__ cursor, u16* __restrict__ msgbuf){
  __shared__ __align__(16) u16 Als[128][136];   // 34816 B; overlaid by msg fp32 [128][68] (same 272 B stride)
  __shared__ __align__(16) u16 Bls[64][136];    // 17408 B
  __shared__ int posIds[128];
  int tid = threadIdx.x, lane = tid & 63, w = tid >> 6;

  // ballot meta resolve: rel = #{r : b >= toff[r+1]}
  int b = blockIdx.x;
  unsigned long long mm = __ballot((lane < N_RELS) && (b >= toff[lane + 1]));
  int rel = __popcll(mm);
  if (rel >= N_RELS) return;                    // uniform across block
  int ts = offs[rel] + ((b - toff[rel]) << 7);
  int vc = offs[rel + 1] - ts; if (vc > 128) vc = 128;

  { // B tile: W1Tb[rel], 64 x 128 bf16 (16 KB)
    int j = tid >> 2, seg = tid & 3;
    const uint4* g = (const uint4*)(W1Tb + ((size_t)rel * 64 + j) * 128) + seg * 4;
    uint4* d = (uint4*)&Bls[j][seg * 32];
    d[0] = g[0]; d[1] = g[1]; d[2] = g[2]; d[3] = g[3];
  }
  // A tile: 128 rows x 256 B, 2 passes, 4 threads/row
  #pragma unroll
  for (int p = 0; p < 2; ++p) {
    int i = p * 64 + (tid >> 2), seg = tid & 3;
    if (i < vc) {
      int e = perm[ts + i];
      if (seg == 0) posIds[i] = atomicAdd(&cursor[dst[e]], 1);  // absolute msg row
      const uint4* g = (const uint4*)(featb + (size_t)src[e] * D_IN) + seg * 4;
      uint4* d = (uint4*)&Als[i][seg * 32];
      d[0] = g[0]; d[1] = g[1]; d[2] = g[2]; d[3] = g[3];
    } else if (seg == 0) posIds[i] = -1;        // pad row: A garbage OK (row-local, discarded)
  }
  __syncthreads();

  int r16 = lane & 15, c4 = lane >> 4;
  // wave w owns rows [w*32, w*32+32): 2 m-tiles
  sfrag aF[2][4];
  #pragma unroll
  for (int mt = 0; mt < 2; ++mt)
    #pragma unroll
    for (int kk = 0; kk < 4; ++kk)
      aF[mt][kk] = *(const sfrag*)&Als[w * 32 + mt * 16 + r16][kk * 32 + c4 * 8];
  f32x4 accAll[2][4];
  #pragma unroll
  for (int ct = 0; ct < 4; ++ct) {
    sfrag bF[4];
    #pragma unroll
    for (int kk = 0; kk < 4; ++kk)
      bF[kk] = *(const sfrag*)&Bls[ct * 16 + r16][kk * 32 + c4 * 8];
    #pragma unroll
    for (int mt = 0; mt < 2; ++mt) {
      f32x4 acc = {0.f, 0.f, 0.f, 0.f};
      #pragma unroll
      for (int kk = 0; kk < 4; ++kk)
        acc = __builtin_amdgcn_mfma_f32_16x16x32_bf16(aF[mt][kk], bF[kk], acc, 0, 0, 0);
      accAll[mt][ct] = acc;
    }
  }
  // msg overlay writes are wave-private (same rows the wave just read its frags from)
  float* msg = (float*)&Als[0][0];              // stride 68 floats == 272 B == Als row
  #pragma unroll
  for (int mt = 0; mt < 2; ++mt)
    #pragma unroll
    for (int ct = 0; ct < 4; ++ct) {
      int col = ct * 16 + r16;
      #pragma unroll
      for (int reg = 0; reg < 4; ++reg) {
        int row = w * 32 + mt * 16 + c4 * 4 + reg;   // D: col=lane&15, row=(lane>>4)*4+reg
        msg[row * 68 + col] = accAll[mt][ct][reg];
      }
    }
  __syncthreads();
  // write-out: thread t -> (row, half), 64 B bf16 per thread, coalesced within row
  { int row = tid >> 1, half = tid & 1;
    int pos = posIds[row];
    if (pos >= 0) {
      const float* mr = msg + row * 68 + half * 32;
      u32 pk[16];
      #pragma unroll
      for (int q = 0; q < 16; ++q)
        pk[q] = (u32)f2bf(mr[2 * q]) | ((u32)f2bf(mr[2 * q + 1]) << 16);
      uint4* d = (uint4*)(msgbuf + (size_t)pos * D_HID + half * 32);
      d[0] = *(uint4*)&pk[0];  d[1] = *(uint4*)&pk[4];
      d[2] = *(uint4*)&pk[8];  d[3] = *(uint4*)&pk[12];
    } }
}

// Fused: CSR message aggregation + self-loop + relu -> h1b (full init),
// plus layer-2 self-loop: out[n,:] = h1 @ loop2 + b2 (full init of out).
__global__ __launch_bounds__(256) void k_agg_relu_self2(
    const u16* __restrict__ msgbuf, const int* __restrict__ dcsr,
    const float* __restrict__ agg1f, const float* __restrict__ loop2,
    const float* __restrict__ b2, u16* __restrict__ h1b,
    float* __restrict__ out){
  int wv = threadIdx.x >> 6, lane = threadIdx.x & 63;
  int n = blockIdx.x * 4 + wv;
  int s = dcsr[n], epos = dcsr[n + 1];
  int h = lane >> 5, c = lane & 31;
  float a0 = 0.f, a1 = 0.f;
  for (int i = s + h; i < epos; i += 2) {
    u32 v = ((const u32*)msgbuf)[(size_t)i * 32 + c];
    a0 += bf2f((u16)(v & 0xffffu));
    a1 += bf2f((u16)(v >> 16));
  }
  a0 += __shfl_down(a0, 32);
  a1 += __shfl_down(a1, 32);
  float p0 = 0.f, p1 = 0.f;
  if (h == 0) {
    float2 sl = ((const float2*)(agg1f + (size_t)n * D_HID))[c];
    float v0 = a0 + sl.x, v1 = a1 + sl.y;
    v0 = v0 > 0.f ? v0 : 0.f;
    v1 = v1 > 0.f ? v1 : 0.f;
    ((u32*)h1b)[(size_t)n * 32 + c] = (u32)f2bf(v0) | ((u32)f2bf(v1) << 16);
    float2 w0 = ((const float2*)loop2)[2 * c];       // loop2 row 2c
    float2 w1 = ((const float2*)loop2)[2 * c + 1];   // loop2 row 2c+1
    p0 = v0 * w0.x + v1 * w1.x;
    p1 = v0 * w0.y + v1 * w1.y;
  }
  #pragma unroll
  for (int off = 16; off; off >>= 1) {
    p0 += __shfl_down(p0, off);
    p1 += __shfl_down(p1, off);
  }
  if (lane == 0) {
    out[n * 2]     = p0 + b2[0];
    out[n * 2 + 1] = p1 + b2[1];
  }
}

// Layer-2 edge messages: 128-edge rel-pure tiles, K=64 bf16 MFMA, cheap 2-col atomics.
__global__ __launch_bounds__(256) void k_edge2_mfma(
    const u16* __restrict__ h1b, const u16* __restrict__ W2Tb,
    const int* __restrict__ src, const int* __restrict__ dst,
    const int* __restrict__ perm, const int* __restrict__ offs,
    const int* __restrict__ toff, float* __restrict__ out){
  __shared__ __align__(16) u16 Als[128][72];
  __shared__ __align__(16) u16 Bls[16][72];
  __shared__ int dstIds[128];
  int tid = threadIdx.x, lane = tid & 63, w = tid >> 6;

  int b = blockIdx.x;
  unsigned long long mm = __ballot((lane < N_RELS) && (b >= toff[lane + 1]));
  int rel = __popcll(mm);
  if (rel >= N_RELS) return;
  int ts = offs[rel] + ((b - toff[rel]) << 7);
  int vc = offs[rel + 1] - ts; if (vc > 128) vc = 128;

  if (tid < 128) {   // B tile: 16 x 64 bf16 = 128 uint4
    ((uint4*)&Bls[tid >> 3][0])[tid & 7] = ((const uint4*)(W2Tb + (size_t)rel * 16 * 64))[tid];
  }
  { // A: 128 rows x 128 B, 2 threads/row
    int i = tid >> 1, half = tid & 1;
    if (i < vc) {
      int e = perm[ts + i];
      if (half == 0) dstIds[i] = dst[e];
      const uint4* g = (const uint4*)(h1b + (size_t)src[e] * D_HID) + half * 4;
      uint4* d = (uint4*)&Als[i][half * 32];
      d[0] = g[0]; d[1] = g[1]; d[2] = g[2]; d[3] = g[3];
    } else if (half == 0) dstIds[i] = -1;
  }
  __syncthreads();

  int r16 = lane & 15, c4 = lane >> 4;
  #pragma unroll
  for (int mt = 0; mt < 2; ++mt) {
    f32x4 acc = {0.f, 0.f, 0.f, 0.f};
    #pragma unroll
    for (int kk = 0; kk < 2; ++kk) {
      sfrag aF = *(const sfrag*)&Als[w * 32 + mt * 16 + r16][kk * 32 + c4 * 8];
      sfrag bF = *(const sfrag*)&Bls[r16][kk * 32 + c4 * 8];
      acc = __builtin_amdgcn_mfma_f32_16x16x32_bf16(aF, bF, acc, 0, 0, 0);
    }
    if (r16 < D_OUT) {
      #pragma unroll
      for (int reg = 0; reg < 4; ++reg) {
        int row = w * 32 + mt * 16 + c4 * 4 + reg;
        int dn = dstIds[row];
        if (dn >= 0) atomicAdd(&out[dn * D_OUT + r16], acc[reg]);
      }
    }
  }
}

extern "C" void kernel_launch(void* const* d_in, const int* in_sizes, int n_in,
                              void* d_out, int out_size, void* d_ws, size_t ws_size,
                              hipStream_t stream){
  const float* feat  = (const float*)d_in[0];
  const float* W1    = (const float*)d_in[1];
  const float* loop1 = (const float*)d_in[2];
  const float* b1    = (const float*)d_in[3];
  const float* W2    = (const float*)d_in[4];
  const float* loop2 = (const float*)d_in[5];
  const float* b2    = (const float*)d_in[6];
  const int* src     = (const int*)d_in[7];
  const int* dst     = (const int*)d_in[8];
  const int* et      = (const int*)d_in[9];
  float* out = (float*)d_out;

  // workspace layout (16B-aligned), ~112 MB total
  char* w = (char*)d_ws;
  u16*   W1Tb     = (u16*)(w);                   //  311296
  u16*   W2Tb     = (u16*)(w + 311296);          //   38912
  u16*   loop1Tb  = (u16*)(w + 350208);          //   16384
  int*   hist_rel = (int*)(w + 366592);
  int*   offs     = (int*)(w + 366720);
  int*   toff     = (int*)(w + 366848);
  int*   cur_rel  = (int*)(w + 366976);
  int*   bsum     = (int*)(w + 367104);          //  784 B -> slot 1024
  int*   boff     = (int*)(w + 368128);          //  784 B -> slot 1024
  int*   hist_dst = (int*)(w + 369152);          //  200000
  int*   dcsr     = (int*)(w + 569152);          //  200016
  int*   cur_dst  = (int*)(w + 769168);          //  200000
  int*   perm     = (int*)(w + 969168);          // 2400000
  u16*   featb    = (u16*)(w + 3369168);         // 12.8 MB
  float* agg1f    = (float*)(w + 16169168);      // 12.8 MB
  u16*   h1b      = (u16*)(w + 28969168);        //  6.4 MB
  u16*   msgbuf   = (u16*)(w + 35369168);        // 76.8 MB -> 112169168

  const int MAX_TILES = (N_EDGES + 127) / 128 + N_RELS;   // 4707

  k_prep          <<<716,   256, 0, stream>>>(W1, loop1, W2, W1Tb, loop1Tb, W2Tb,
                                              hist_rel, hist_dst);
  k_fused_pre     <<<12500, 256, 0, stream>>>(feat, featb, et, dst, hist_rel, hist_dst);
  k_scan_rel      <<<1,      64, 0, stream>>>(hist_rel, offs, toff, cur_rel);
  k_scan_dst1     <<<196,   256, 0, stream>>>(hist_dst, dcsr, bsum);
  k_scan_dst2     <<<1,     256, 0, stream>>>(bsum, boff);
  k_scan_dst3     <<<196,   256, 0, stream>>>(boff, dcsr, cur_dst);
  k_scatter_rel   <<<2344,  256, 0, stream>>>(et, cur_rel, perm);
  k_selfloop1_mfma<<<(N_NODES + 63) / 64, 256, 0, stream>>>(featb, loop1Tb, b1, agg1f);
  k_edge1_mfma    <<<MAX_TILES, 256, 0, stream>>>(featb, W1Tb, src, dst, perm, offs, toff,
                                                  dcsr, cur_dst, msgbuf);
  k_agg_relu_self2<<<12500, 256, 0, stream>>>(msgbuf, dcsr, agg1f, loop2, b2, h1b, out);
  k_edge2_mfma    <<<MAX_TILES, 256, 0, stream>>>(h1b, W2Tb, src, dst, perm, offs, toff, out);
}